// Round 4
// baseline (351.121 us; speedup 1.0000x reference)
//
#include <hip/hip_runtime.h>

typedef unsigned short u16;
typedef unsigned int u32;
typedef short v8s __attribute__((ext_vector_type(8)));
typedef float v4f __attribute__((ext_vector_type(4)));
typedef float v16f __attribute__((ext_vector_type(16)));

#define MFMA16(a, b, c) __builtin_amdgcn_mfma_f32_16x16x32_bf16((a), (b), (c), 0, 0, 0)
#define MFMA32(a, b, c) __builtin_amdgcn_mfma_f32_32x32x16_bf16((a), (b), (c), 0, 0, 0)

static __device__ __forceinline__ u16 f2bf(float f) {
    u32 u = __float_as_uint(f);
    u += 0x7fffu + ((u >> 16) & 1u);   // RNE
    return (u16)(u >> 16);
}

// async global->LDS, 16B per lane. LDS dest must be wave-uniform base + lane*16.
static __device__ __forceinline__ void gl2lds(const u16* g, u16* l) {
    __builtin_amdgcn_global_load_lds(
        (const __attribute__((address_space(1))) void*)g,
        (__attribute__((address_space(3))) void*)l, 16, 0, 0);
}

// ---------------------------------------------------------------------------
// prep: fp32 weights -> bf16 (Wqkv packed [1536][512], Wp [512][512]), bias pack
// ---------------------------------------------------------------------------
__global__ __launch_bounds__(256) void prep_kernel(
    const float* __restrict__ wq, const float* __restrict__ wk,
    const float* __restrict__ wv, const float* __restrict__ wp,
    const float* __restrict__ bq, const float* __restrict__ bk,
    const float* __restrict__ bv,
    u16* __restrict__ Wqkv, u16* __restrict__ Wp, float* __restrict__ bqkv) {
    int id = blockIdx.x * 256 + threadIdx.x;   // 0 .. 1048575
    float v;
    if (id < 262144)       v = wq[id];
    else if (id < 524288)  v = wk[id - 262144];
    else if (id < 786432)  v = wv[id - 524288];
    else                   v = wp[id - 786432];
    if (id < 786432) Wqkv[id] = f2bf(v);
    else             Wp[id - 786432] = f2bf(v);
    if (id < 1536) {
        float b = (id < 512) ? bq[id] : (id < 1024 ? bk[id - 512] : bv[id - 1024]);
        bqkv[id] = b;
    }
}

// ---------------------------------------------------------------------------
// GroupNorm pass 1: per (b,g) mean & rsigma over 16 ch x 1024 spatial
// ---------------------------------------------------------------------------
__global__ __launch_bounds__(256) void gn_stats(const float* __restrict__ x,
                                                float2* __restrict__ stats) {
    int g = blockIdx.x, b = blockIdx.y;
    const float4* x4 = (const float4*)x + (size_t)(b * 512 + g * 16) * 256;
    float s = 0.f, s2 = 0.f;
    for (int i = threadIdx.x; i < 4096; i += 256) {
        float4 v = x4[i];
        s  += v.x + v.y + v.z + v.w;
        s2 += v.x * v.x + v.y * v.y + v.z * v.z + v.w * v.w;
    }
    #pragma unroll
    for (int d = 1; d < 64; d <<= 1) { s += __shfl_xor(s, d); s2 += __shfl_xor(s2, d); }
    __shared__ float red1[4], red2[4];
    int w = threadIdx.x >> 6;
    if ((threadIdx.x & 63) == 0) { red1[w] = s; red2[w] = s2; }
    __syncthreads();
    if (threadIdx.x == 0) {
        s = red1[0] + red1[1] + red1[2] + red1[3];
        s2 = red2[0] + red2[1] + red2[2] + red2[3];
        float mu = s * (1.0f / 16384.0f);
        float var = s2 * (1.0f / 16384.0f) - mu * mu;
        stats[b * 32 + g] = make_float2(mu, rsqrtf(var + 1e-5f));
    }
}

// ---------------------------------------------------------------------------
// GroupNorm pass 2 + transpose: x[b,c,s] fp32 -> h[b*1024+s][c] bf16 (token-major)
// ---------------------------------------------------------------------------
__global__ __launch_bounds__(256) void gn_apply(
    const float* __restrict__ x, const float2* __restrict__ stats,
    const float* __restrict__ gnw, const float* __restrict__ gnb,
    u16* __restrict__ h) {
    int st = blockIdx.x, b = blockIdx.y;
    int s0 = st * 64;
    __shared__ float smu[32], srs[32], sw[512], sbv[512];
    __shared__ alignas(16) u16 hs[64][520];
    int t = threadIdx.x;
    if (t < 32) { float2 v = stats[b * 32 + t]; smu[t] = v.x; srs[t] = v.y; }
    sw[t] = gnw[t]; sw[t + 256] = gnw[t + 256];
    sbv[t] = gnb[t]; sbv[t + 256] = gnb[t + 256];
    __syncthreads();
    #pragma unroll 4
    for (int it = 0; it < 32; ++it) {
        int id = it * 256 + t;
        int c = id >> 4, f4 = id & 15;
        float4 v = ((const float4*)x)[(size_t)(b * 512 + c) * 256 + (s0 >> 2) + f4];
        int g = c >> 4;
        float mu = smu[g], r = srs[g], wgt = sw[c], bia = sbv[c];
        hs[f4 * 4 + 0][c] = f2bf((v.x - mu) * r * wgt + bia);
        hs[f4 * 4 + 1][c] = f2bf((v.y - mu) * r * wgt + bia);
        hs[f4 * 4 + 2][c] = f2bf((v.z - mu) * r * wgt + bia);
        hs[f4 * 4 + 3][c] = f2bf((v.w - mu) * r * wgt + bia);
    }
    __syncthreads();
    int lane = t & 63, wrow = t >> 6;
    #pragma unroll 4
    for (int it = 0; it < 16; ++it) {
        int s = it * 4 + wrow;
        float4 vv = *(const float4*)&hs[s][lane * 8];
        *((float4*)h + (size_t)(b * 1024 + s0 + s) * 64 + lane) = vv;
    }
}

// ---------------------------------------------------------------------------
// QKV GEMM. Q: token-major, pre-scaled by 512^-0.5.
// K: per-(batch, 32-key tile) image [32 key][512 ch]; 16B blocks (64/row)
//    XOR-swizzled by (key&7).
// V: per-tile image [512 ch][32 key]; 16B blocks (4/row) XOR-swizzled by
//    ((ch>>1)&3). Both images copied verbatim to LDS by flash_attn.
// ---------------------------------------------------------------------------
__global__ __launch_bounds__(256, 2) void gemm_qkv(
    const u16* __restrict__ h, const u16* __restrict__ Wqkv,
    const float* __restrict__ bqkv,
    u16* __restrict__ Qo, u16* __restrict__ Ko, u16* __restrict__ Vo) {
    int n0 = blockIdx.x * 128, m0 = blockIdx.y * 128;
    __shared__ alignas(16) u16 As[128][32];
    __shared__ alignas(16) u16 Bs[128][32];
    __shared__ alignas(16) u16 Tr[128][136];
    int t = threadIdx.x, w = t >> 6, l = t & 63;
    int lane16 = l & 15, quad = l >> 4;
    int wm = w & 1, wn = w >> 1;
    v4f acc[4][4] = {};
    for (int k0 = 0; k0 < 512; k0 += 32) {
        #pragma unroll
        for (int i = 0; i < 2; ++i) {
            int id = i * 256 + t, row = id >> 2, c16 = id & 3;
            gl2lds(&h[(size_t)(m0 + row) * 512 + k0 + c16 * 8], &As[row][c16 * 8]);
            gl2lds(&Wqkv[(size_t)(n0 + row) * 512 + k0 + c16 * 8], &Bs[row][c16 * 8]);
        }
        __syncthreads();
        v8s af[4], bf[4];
        #pragma unroll
        for (int i = 0; i < 4; ++i)
            af[i] = *(const v8s*)&As[wm * 64 + i * 16 + lane16][quad * 8];
        #pragma unroll
        for (int j = 0; j < 4; ++j)
            bf[j] = *(const v8s*)&Bs[wn * 64 + j * 16 + lane16][quad * 8];
        #pragma unroll
        for (int i = 0; i < 4; ++i)
            #pragma unroll
            for (int j = 0; j < 4; ++j)
                acc[i][j] = MFMA16(af[i], bf[j], acc[i][j]);
        __syncthreads();
    }
    float bias[4];
    #pragma unroll
    for (int j = 0; j < 4; ++j) bias[j] = bqkv[n0 + wn * 64 + j * 16 + lane16];

    if (n0 < 1024) {
        // Q or K: stage [token][channel] tile in LDS
        const float qscale = (n0 < 512) ? 0.04419417382415922f : 1.0f;
        #pragma unroll
        for (int i = 0; i < 4; ++i)
            #pragma unroll
            for (int j = 0; j < 4; ++j)
                #pragma unroll
                for (int r = 0; r < 4; ++r) {
                    int row = wm * 64 + i * 16 + quad * 4 + r;
                    int col = wn * 64 + j * 16 + lane16;
                    Tr[row][col] = f2bf((acc[i][j][r] + bias[j]) * qscale);
                }
        __syncthreads();
        if (n0 < 512) {
            #pragma unroll
            for (int it = 0; it < 8; ++it) {
                int id = it * 256 + t, row = id >> 4, ch = id & 15;
                *(float4*)&Qo[(size_t)(m0 + row) * 512 + n0 + ch * 8] =
                    *(const float4*)&Tr[row][ch * 8];
            }
        } else {
            int c0 = n0 - 512, b = m0 >> 10, sb = m0 & 1023;
            #pragma unroll
            for (int it = 0; it < 8; ++it) {
                int id = it * 256 + t, row = id >> 4, ch = id & 15;
                int s = sb + row, kt = s >> 5, key = s & 31;
                int kb = ((c0 + ch * 8) >> 3) ^ (key & 7);   // XOR swizzle (64 blocks/row)
                *(float4*)&Ko[((size_t)(b * 32 + kt)) * 16384 + key * 512 + kb * 8] =
                    *(const float4*)&Tr[row][ch * 8];
            }
        }
    } else {
        // V: stage TRANSPOSED [channel][token] in LDS
        #pragma unroll
        for (int i = 0; i < 4; ++i)
            #pragma unroll
            for (int j = 0; j < 4; ++j)
                #pragma unroll
                for (int r = 0; r < 4; ++r) {
                    int row = wm * 64 + i * 16 + quad * 4 + r;
                    int col = wn * 64 + j * 16 + lane16;
                    Tr[col][row] = f2bf(acc[i][j][r] + bias[j]);
                }
        __syncthreads();
        int c0 = n0 - 1024, b = m0 >> 10, sb = m0 & 1023;
        #pragma unroll
        for (int it = 0; it < 8; ++it) {
            int id = it * 256 + t, c = id >> 4, ch8 = id & 15;
            int key0 = sb + ch8 * 8;                  // 8 consecutive keys
            int kt = key0 >> 5;
            int kblk = (key0 >> 3) & 3;               // block within 4-block row
            int ch = c0 + c;
            int swz = (ch >> 1) & 3;
            *(float4*)&Vo[((size_t)(b * 32 + kt)) * 16384 + (size_t)ch * 32 +
                          ((kblk ^ swz) * 8)] =
                *(const float4*)&Tr[c][ch8 * 8];
        }
    }
}

// ---------------------------------------------------------------------------
// Flash attention v7: v3's staging/sync structure (K+V LDS-staged, double-
// buffered, one barrier per tile — the LDS staging IS the prefetch; rounds
// 1/3 proved taking V off it exposes latency) + two LDS-instr reductions:
//  * consumers channel-split (each wave owns a 128-ch quarter x all 64 q):
//    V ds_reads 64->32 KB/tile. NO setprio (lockstep regime, regressed in v5).
//  * producers compute SWAPPED QK: MFMA16(Kfrag, Qfrag) -> S[key][q] with
//    q=lane16, keys=quad*4+r. The 4 per-lane P values are key-consecutive:
//    ONE ds_write_b64 per query-half (2 vs 8 LDS writes/wave/tile), same
//    swizzled P image as before (consumer reads unchanged). l-reduce becomes
//    2 shfl_xor across quads instead of 32.
// ---------------------------------------------------------------------------
__global__ __launch_bounds__(512, 2) void flash_attn(
    const u16* __restrict__ Q, const u16* __restrict__ Kt,
    const u16* __restrict__ Vt, u16* __restrict__ O) {
    int idx = blockIdx.x;
    int xcd = idx & 7, j = idx >> 3;          // XCD-aware: 4 batches per XCD
    int bz = xcd * 4 + (j >> 4);
    int qb = j & 15;                          // 64-query block

    __shared__ alignas(16) char lds[139776];
    u16*   KsB  = (u16*)lds;                  // [2][32][512]  64 KB
    u16*   VsB  = (u16*)(lds + 65536);        // [2][512][32]  64 KB
    u16*   Pb   = (u16*)(lds + 131072);       // [2][64][32]    8 KB
    float* lsum = (float*)(lds + 139264);     // [2][64]      0.5 KB

    int t = threadIdx.x, w = t >> 6, l = t & 63;
    int lane16 = l & 15, quad = l >> 4;
    int s5 = l >> 5, l31 = l & 31;

    const u16* Kb = Kt + (size_t)bz * 32 * 16384;
    const u16* Vb = Vt + (size_t)bz * 32 * 16384;

    // prologue: stage K tile 0 (each wave copies 4 KB of the 32 KB tile)
    #pragma unroll
    for (int c = 0; c < 4; ++c) {
        int ch = w * 4 + c;
        gl2lds(&Kb[ch * 512 + l * 8], &KsB[ch * 512 + l * 8]);
    }
    __syncthreads();

    if (w < 4) {
        // ================= PRODUCER =================
        int qs = w & 1, kh = w >> 1;
        int qrow = bz * 1024 + qb * 64 + qs * 32 + lane16;
        v8s qf0[16], qf1[16];
        #pragma unroll
        for (int kk = 0; kk < 16; ++kk) {
            qf0[kk] = *(const v8s*)&Q[(size_t)qrow * 512 + kk * 32 + quad * 8];
            qf1[kk] = *(const v8s*)&Q[(size_t)(qrow + 16) * 512 + kk * 32 + quad * 8];
        }
        float liA = 0.f, liB = 0.f;
        int key = kh * 16 + lane16;
        int krowoff = key * 512;
        int kswz = lane16 & 7;
        // packed P-write constants: this lane writes keys kh*16+quad*4..+3
        int qA = qs * 32 + lane16, qB = qA + 16;
        int blk = kh * 2 + (quad >> 1);
        int pwA = qA * 32 + ((blk ^ ((qA >> 1) & 3)) * 8) + (quad & 1) * 4;
        int pwB = qB * 32 + ((blk ^ ((qB >> 1) & 3)) * 8) + (quad & 1) * 4;

        for (int kt = 0; kt <= 32; ++kt) {
            if (kt + 1 < 32) {
                u16* kd = KsB + ((kt + 1) & 1) * 16384;
                const u16* ks = Kb + (size_t)(kt + 1) * 16384;
                #pragma unroll
                for (int c = 0; c < 4; ++c) {
                    int ch = w * 4 + c;
                    gl2lds(&ks[ch * 512 + l * 8], &kd[ch * 512 + l * 8]);
                }
            }
            if (kt < 32) {
                u16* vd = VsB + (kt & 1) * 16384;
                const u16* vs = Vb + (size_t)kt * 16384;
                #pragma unroll
                for (int c = 0; c < 4; ++c) {
                    int ch = w * 4 + c;
                    gl2lds(&vs[ch * 512 + l * 8], &vd[ch * 512 + l * 8]);
                }
                const u16* KsT = KsB + (kt & 1) * 16384;
                u16* Pt = Pb + (kt & 1) * 2048;
                v4f sA = {}, sB = {};
                #pragma unroll
                for (int kk = 0; kk < 16; ++kk) {
                    v8s b = *(const v8s*)&KsT[krowoff + (((kk * 4 + quad) ^ kswz) * 8)];
                    sA = MFMA16(b, qf0[kk], sA);   // S[key][q], q = lane16
                    sB = MFMA16(b, qf1[kk], sB);
                }
                float a0 = __expf(sA[0]), a1 = __expf(sA[1]);
                float a2 = __expf(sA[2]), a3 = __expf(sA[3]);
                float b0 = __expf(sB[0]), b1 = __expf(sB[1]);
                float b2 = __expf(sB[2]), b3 = __expf(sB[3]);
                liA += (a0 + a1) + (a2 + a3);
                liB += (b0 + b1) + (b2 + b3);
                uint2 pkA, pkB;
                pkA.x = (u32)f2bf(a0) | ((u32)f2bf(a1) << 16);
                pkA.y = (u32)f2bf(a2) | ((u32)f2bf(a3) << 16);
                pkB.x = (u32)f2bf(b0) | ((u32)f2bf(b1) << 16);
                pkB.y = (u32)f2bf(b2) | ((u32)f2bf(b3) << 16);
                *(uint2*)&Pt[pwA] = pkA;
                *(uint2*)&Pt[pwB] = pkB;
            }
            __syncthreads();
        }
        // reduce l across the 4 quads (each holds 4 of this wave's 16 keys)
        liA += __shfl_xor(liA, 16); liA += __shfl_xor(liA, 32);
        liB += __shfl_xor(liB, 16); liB += __shfl_xor(liB, 32);
        if (l < 16) {
            lsum[kh * 64 + qs * 32 + lane16] = liA;
            lsum[kh * 64 + qs * 32 + 16 + lane16] = liB;
        }
        __syncthreads();
    } else {
        // ================= CONSUMER (channel-split) =================
        int chq = w - 4;                       // 128-channel quarter
        v16f acc[4][2] = {};                   // [chb][qh]
        int q0 = l31, q1 = 32 + l31;
        int psw0 = (q0 >> 1) & 3, psw1 = (q1 >> 1) & 3;

        for (int kt = 0; kt <= 32; ++kt) {
            if (kt + 1 < 32) {
                u16* kd = KsB + ((kt + 1) & 1) * 16384;
                const u16* ks = Kb + (size_t)(kt + 1) * 16384;
                #pragma unroll
                for (int c = 0; c < 4; ++c) {
                    int ch = w * 4 + c;
                    gl2lds(&ks[ch * 512 + l * 8], &kd[ch * 512 + l * 8]);
                }
            }
            if (kt < 32) {
                u16* vd = VsB + (kt & 1) * 16384;
                const u16* vs = Vb + (size_t)kt * 16384;
                #pragma unroll
                for (int c = 0; c < 4; ++c) {
                    int ch = w * 4 + c;
                    gl2lds(&vs[ch * 512 + l * 8], &vd[ch * 512 + l * 8]);
                }
            }
            if (kt >= 1) {
                int kp = (kt - 1) & 1;
                const u16* Pt  = Pb + kp * 2048;
                const u16* VsT = VsB + kp * 16384;
                #pragma unroll
                for (int kc = 0; kc < 2; ++kc) {
                    v8s pb0 = *(const v8s*)&Pt[q0 * 32 + (((kc * 2 + s5) ^ psw0) * 8)];
                    v8s pb1 = *(const v8s*)&Pt[q1 * 32 + (((kc * 2 + s5) ^ psw1) * 8)];
                    #pragma unroll
                    for (int chb = 0; chb < 4; ++chb) {
                        int ch = chq * 128 + chb * 32 + l31;
                        v8s vf = *(const v8s*)&VsT[ch * 32 +
                                                   (((kc * 2 + s5) ^ ((ch >> 1) & 3)) * 8)];
                        acc[chb][0] = MFMA32(vf, pb0, acc[chb][0]);
                        acc[chb][1] = MFMA32(vf, pb1, acc[chb][1]);
                    }
                }
            }
            __syncthreads();
        }
        __syncthreads();   // wait for lsum
        float inv0 = 1.0f / (lsum[q0] + lsum[64 + q0]);
        float inv1 = 1.0f / (lsum[q1] + lsum[64 + q1]);
        int tok0 = bz * 1024 + qb * 64 + q0;
        int tok1 = tok0 + 32;
        #pragma unroll
        for (int chb = 0; chb < 4; ++chb) {
            #pragma unroll
            for (int rg = 0; rg < 4; ++rg) {
                int ch0 = chq * 128 + chb * 32 + rg * 8 + s5 * 4;
                u16 o4[4];
                #pragma unroll
                for (int i = 0; i < 4; ++i) o4[i] = f2bf(acc[chb][0][rg * 4 + i] * inv0);
                *(uint2*)&O[(size_t)tok0 * 512 + ch0] = *(const uint2*)o4;
                #pragma unroll
                for (int i = 0; i < 4; ++i) o4[i] = f2bf(acc[chb][1][rg * 4 + i] * inv1);
                *(uint2*)&O[(size_t)tok1 * 512 + ch0] = *(const uint2*)o4;
            }
        }
    }
}

// ---------------------------------------------------------------------------
// Proj GEMM + residual: out[b][c][token] = x + Wp @ O_b^T + bp
// ---------------------------------------------------------------------------
__global__ __launch_bounds__(256, 2) void gemm_proj(
    const u16* __restrict__ Wp, const u16* __restrict__ O,
    const float* __restrict__ x, const float* __restrict__ bp,
    float* __restrict__ out) {
    int n0 = blockIdx.x * 128, m0 = blockIdx.y * 128, b = blockIdx.z;
    __shared__ alignas(16) u16 As[128][32];
    __shared__ alignas(16) u16 Bs[128][32];
    int t = threadIdx.x, w = t >> 6, l = t & 63;
    int lane16 = l & 15, quad = l >> 4;
    int wm = w & 1, wn = w >> 1;
    v4f acc[4][4] = {};
    for (int k0 = 0; k0 < 512; k0 += 32) {
        #pragma unroll
        for (int i = 0; i < 2; ++i) {
            int id = i * 256 + t, row = id >> 2, c16 = id & 3;
            gl2lds(&Wp[(size_t)(m0 + row) * 512 + k0 + c16 * 8], &As[row][c16 * 8]);
            gl2lds(&O[(size_t)(b * 1024 + n0 + row) * 512 + k0 + c16 * 8], &Bs[row][c16 * 8]);
        }
        __syncthreads();
        v8s af[4], bf[4];
        #pragma unroll
        for (int i = 0; i < 4; ++i)
            af[i] = *(const v8s*)&As[wm * 64 + i * 16 + lane16][quad * 8];
        #pragma unroll
        for (int j = 0; j < 4; ++j)
            bf[j] = *(const v8s*)&Bs[wn * 64 + j * 16 + lane16][quad * 8];
        #pragma unroll
        for (int i = 0; i < 4; ++i)
            #pragma unroll
            for (int j = 0; j < 4; ++j)
                acc[i][j] = MFMA16(af[i], bf[j], acc[i][j]);
        __syncthreads();
    }
    #pragma unroll
    for (int i = 0; i < 4; ++i) {
        #pragma unroll
        for (int r = 0; r < 4; ++r) {
            int row = wm * 64 + i * 16 + quad * 4 + r;
            float bia = bp[m0 + row];
            #pragma unroll
            for (int j = 0; j < 4; ++j) {
                int col = wn * 64 + j * 16 + lane16;
                size_t idx = (size_t)(b * 512 + m0 + row) * 1024 + n0 + col;
                out[idx] = acc[i][j][r] + bia + x[idx];
            }
        }
    }
}

// ---------------------------------------------------------------------------
extern "C" void kernel_launch(void* const* d_in, const int* in_sizes, int n_in,
                              void* d_out, int out_size, void* d_ws, size_t ws_size,
                              hipStream_t stream) {
    (void)in_sizes; (void)n_in; (void)out_size; (void)ws_size;
    const float* x   = (const float*)d_in[0];
    const float* gnw = (const float*)d_in[1];
    const float* gnb = (const float*)d_in[2];
    const float* wq  = (const float*)d_in[3];
    const float* bq  = (const float*)d_in[4];
    const float* wk  = (const float*)d_in[5];
    const float* bk  = (const float*)d_in[6];
    const float* wv  = (const float*)d_in[7];
    const float* bv  = (const float*)d_in[8];
    const float* wp  = (const float*)d_in[9];
    const float* bp  = (const float*)d_in[10];
    float* out = (float*)d_out;

    char* ws = (char*)d_ws;
    u16*    Wqkv  = (u16*)(ws + 0);                       // 1.5 MB
    u16*    Wp    = (u16*)(ws + 1572864);                 // 0.5 MB
    float*  bqkv  = (float*)(ws + 2097152);               // 6 KB
    float2* stats = (float2*)(ws + 2105344);              // 8 KB
    u16*    h     = (u16*)(ws + 4194304ULL);              // 32 MB (reused as O)
    u16*    Qb    = (u16*)(ws + 4194304ULL + 33554432ULL);        // 32 MB
    u16*    Kb    = (u16*)(ws + 4194304ULL + 2ULL * 33554432ULL); // 32 MB tiled/swizzled
    u16*    Vb    = (u16*)(ws + 4194304ULL + 3ULL * 33554432ULL); // 32 MB tiled/swizzled

    prep_kernel<<<4096, 256, 0, stream>>>(wq, wk, wv, wp, bq, bk, bv, Wqkv, Wp, bqkv);
    gn_stats<<<dim3(32, 32), 256, 0, stream>>>(x, stats);
    gn_apply<<<dim3(16, 32), 256, 0, stream>>>(x, stats, gnw, gnb, h);
    gemm_qkv<<<dim3(12, 256), 256, 0, stream>>>(h, Wqkv, bqkv, Qb, Kb, Vb);
    flash_attn<<<512, 512, 0, stream>>>(Qb, Kb, Vb, h /* -> O */);
    gemm_proj<<<dim3(8, 4, 32), 256, 0, stream>>>(Wp, h /* O */, x, bp, out);
}

// Round 5
// 347.394 us; speedup vs baseline: 1.0107x; 1.0107x over previous
//
#include <hip/hip_runtime.h>

typedef unsigned short u16;
typedef unsigned int u32;
typedef short v8s __attribute__((ext_vector_type(8)));
typedef float v4f __attribute__((ext_vector_type(4)));
typedef float v16f __attribute__((ext_vector_type(16)));

#define MFMA16(a, b, c) __builtin_amdgcn_mfma_f32_16x16x32_bf16((a), (b), (c), 0, 0, 0)
#define MFMA32(a, b, c) __builtin_amdgcn_mfma_f32_32x32x16_bf16((a), (b), (c), 0, 0, 0)

static __device__ __forceinline__ u16 f2bf(float f) {
    u32 u = __float_as_uint(f);
    u += 0x7fffu + ((u >> 16) & 1u);   // RNE
    return (u16)(u >> 16);
}

// async global->LDS, 16B per lane. LDS dest must be wave-uniform base + lane*16.
static __device__ __forceinline__ void gl2lds(const u16* g, u16* l) {
    __builtin_amdgcn_global_load_lds(
        (const __attribute__((address_space(1))) void*)g,
        (__attribute__((address_space(3))) void*)l, 16, 0, 0);
}

// ---------------------------------------------------------------------------
// prep: fp32 weights -> bf16 (Wqkv packed [1536][512], Wp [512][512]), bias pack
// ---------------------------------------------------------------------------
__global__ __launch_bounds__(256) void prep_kernel(
    const float* __restrict__ wq, const float* __restrict__ wk,
    const float* __restrict__ wv, const float* __restrict__ wp,
    const float* __restrict__ bq, const float* __restrict__ bk,
    const float* __restrict__ bv,
    u16* __restrict__ Wqkv, u16* __restrict__ Wp, float* __restrict__ bqkv) {
    int id = blockIdx.x * 256 + threadIdx.x;   // 0 .. 1048575
    float v;
    if (id < 262144)       v = wq[id];
    else if (id < 524288)  v = wk[id - 262144];
    else if (id < 786432)  v = wv[id - 524288];
    else                   v = wp[id - 786432];
    if (id < 786432) Wqkv[id] = f2bf(v);
    else             Wp[id - 786432] = f2bf(v);
    if (id < 1536) {
        float b = (id < 512) ? bq[id] : (id < 1024 ? bk[id - 512] : bv[id - 1024]);
        bqkv[id] = b;
    }
}

// ---------------------------------------------------------------------------
// GroupNorm pass 1: per (b,g) mean & rsigma over 16 ch x 1024 spatial
// ---------------------------------------------------------------------------
__global__ __launch_bounds__(256) void gn_stats(const float* __restrict__ x,
                                                float2* __restrict__ stats) {
    int g = blockIdx.x, b = blockIdx.y;
    const float4* x4 = (const float4*)x + (size_t)(b * 512 + g * 16) * 256;
    float s = 0.f, s2 = 0.f;
    for (int i = threadIdx.x; i < 4096; i += 256) {
        float4 v = x4[i];
        s  += v.x + v.y + v.z + v.w;
        s2 += v.x * v.x + v.y * v.y + v.z * v.z + v.w * v.w;
    }
    #pragma unroll
    for (int d = 1; d < 64; d <<= 1) { s += __shfl_xor(s, d); s2 += __shfl_xor(s2, d); }
    __shared__ float red1[4], red2[4];
    int w = threadIdx.x >> 6;
    if ((threadIdx.x & 63) == 0) { red1[w] = s; red2[w] = s2; }
    __syncthreads();
    if (threadIdx.x == 0) {
        s = red1[0] + red1[1] + red1[2] + red1[3];
        s2 = red2[0] + red2[1] + red2[2] + red2[3];
        float mu = s * (1.0f / 16384.0f);
        float var = s2 * (1.0f / 16384.0f) - mu * mu;
        stats[b * 32 + g] = make_float2(mu, rsqrtf(var + 1e-5f));
    }
}

// ---------------------------------------------------------------------------
// GroupNorm pass 2 + transpose: x[b,c,s] fp32 -> h[b*1024+s][c] bf16 (token-major)
// ---------------------------------------------------------------------------
__global__ __launch_bounds__(256) void gn_apply(
    const float* __restrict__ x, const float2* __restrict__ stats,
    const float* __restrict__ gnw, const float* __restrict__ gnb,
    u16* __restrict__ h) {
    int st = blockIdx.x, b = blockIdx.y;
    int s0 = st * 64;
    __shared__ float smu[32], srs[32], sw[512], sbv[512];
    __shared__ alignas(16) u16 hs[64][520];
    int t = threadIdx.x;
    if (t < 32) { float2 v = stats[b * 32 + t]; smu[t] = v.x; srs[t] = v.y; }
    sw[t] = gnw[t]; sw[t + 256] = gnw[t + 256];
    sbv[t] = gnb[t]; sbv[t + 256] = gnb[t + 256];
    __syncthreads();
    #pragma unroll 4
    for (int it = 0; it < 32; ++it) {
        int id = it * 256 + t;
        int c = id >> 4, f4 = id & 15;
        float4 v = ((const float4*)x)[(size_t)(b * 512 + c) * 256 + (s0 >> 2) + f4];
        int g = c >> 4;
        float mu = smu[g], r = srs[g], wgt = sw[c], bia = sbv[c];
        hs[f4 * 4 + 0][c] = f2bf((v.x - mu) * r * wgt + bia);
        hs[f4 * 4 + 1][c] = f2bf((v.y - mu) * r * wgt + bia);
        hs[f4 * 4 + 2][c] = f2bf((v.z - mu) * r * wgt + bia);
        hs[f4 * 4 + 3][c] = f2bf((v.w - mu) * r * wgt + bia);
    }
    __syncthreads();
    int lane = t & 63, wrow = t >> 6;
    #pragma unroll 4
    for (int it = 0; it < 16; ++it) {
        int s = it * 4 + wrow;
        float4 vv = *(const float4*)&hs[s][lane * 8];
        *((float4*)h + (size_t)(b * 1024 + s0 + s) * 64 + lane) = vv;
    }
}

// ---------------------------------------------------------------------------
// QKV GEMM, BK=64 (8 K-phases instead of 16 — halves barrier/drain count).
// As/Bs [128][64] with XOR block swizzle: LDS block b of row r holds global
// col-block b^(r&7) (pre-swizzled SOURCE address, linear gl2lds dest — rule
// #21). Fragment reads use block ((h*4+quad)^(lane16&7)) -> bank-balanced
// (8 lanes cover all 32 banks). Epilogue Tr overlays As/Bs (dead after last
// fragment load) so static LDS = 34.8 KB.
// Q: token-major, pre-scaled by 512^-0.5.
// K: per-(batch, 32-key tile) image [32 key][512 ch]; 16B blocks (64/row)
//    XOR-swizzled by (key&7).
// V: per-tile image [512 ch][32 key]; 16B blocks (4/row) XOR-swizzled by
//    ((ch>>1)&3). Both images copied verbatim to LDS by flash_attn.
// ---------------------------------------------------------------------------
__global__ __launch_bounds__(256, 2) void gemm_qkv(
    const u16* __restrict__ h, const u16* __restrict__ Wqkv,
    const float* __restrict__ bqkv,
    u16* __restrict__ Qo, u16* __restrict__ Ko, u16* __restrict__ Vo) {
    int n0 = blockIdx.x * 128, m0 = blockIdx.y * 128;
    __shared__ alignas(16) char ldsb[34816];
    u16* As = (u16*)ldsb;             // [128][64] during K-loop
    u16* Bs = (u16*)(ldsb + 16384);   // [128][64] during K-loop
    u16* Tr = (u16*)ldsb;             // [128][136] epilogue overlay
    int t = threadIdx.x, w = t >> 6, l = t & 63;
    int lane16 = l & 15, quad = l >> 4;
    int wm = w & 1, wn = w >> 1;
    v4f acc[4][4] = {};
    for (int k0 = 0; k0 < 512; k0 += 64) {
        #pragma unroll
        for (int i = 0; i < 4; ++i) {
            int id = i * 256 + t, row = id >> 3, c16 = id & 7;
            int sc = c16 ^ (row & 7);          // source col-block (swizzle inverse)
            gl2lds(&h[(size_t)(m0 + row) * 512 + k0 + sc * 8], &As[row * 64 + c16 * 8]);
            gl2lds(&Wqkv[(size_t)(n0 + row) * 512 + k0 + sc * 8], &Bs[row * 64 + c16 * 8]);
        }
        __syncthreads();
        #pragma unroll
        for (int hh = 0; hh < 2; ++hh) {
            v8s af[4], bf[4];
            #pragma unroll
            for (int i = 0; i < 4; ++i) {
                int row = wm * 64 + i * 16 + lane16;
                af[i] = *(const v8s*)&As[row * 64 + (((hh * 4 + quad) ^ (lane16 & 7)) * 8)];
            }
            #pragma unroll
            for (int j = 0; j < 4; ++j) {
                int row = wn * 64 + j * 16 + lane16;
                bf[j] = *(const v8s*)&Bs[row * 64 + (((hh * 4 + quad) ^ (lane16 & 7)) * 8)];
            }
            #pragma unroll
            for (int i = 0; i < 4; ++i)
                #pragma unroll
                for (int j = 0; j < 4; ++j)
                    acc[i][j] = MFMA16(af[i], bf[j], acc[i][j]);
        }
        __syncthreads();
    }
    float bias[4];
    #pragma unroll
    for (int j = 0; j < 4; ++j) bias[j] = bqkv[n0 + wn * 64 + j * 16 + lane16];

    if (n0 < 1024) {
        // Q or K: stage [token][channel] tile in LDS (Tr overlays As/Bs)
        const float qscale = (n0 < 512) ? 0.04419417382415922f : 1.0f;
        #pragma unroll
        for (int i = 0; i < 4; ++i)
            #pragma unroll
            for (int j = 0; j < 4; ++j)
                #pragma unroll
                for (int r = 0; r < 4; ++r) {
                    int row = wm * 64 + i * 16 + quad * 4 + r;
                    int col = wn * 64 + j * 16 + lane16;
                    Tr[row * 136 + col] = f2bf((acc[i][j][r] + bias[j]) * qscale);
                }
        __syncthreads();
        if (n0 < 512) {
            #pragma unroll
            for (int it = 0; it < 8; ++it) {
                int id = it * 256 + t, row = id >> 4, ch = id & 15;
                *(float4*)&Qo[(size_t)(m0 + row) * 512 + n0 + ch * 8] =
                    *(const float4*)&Tr[row * 136 + ch * 8];
            }
        } else {
            int c0 = n0 - 512, b = m0 >> 10, sb = m0 & 1023;
            #pragma unroll
            for (int it = 0; it < 8; ++it) {
                int id = it * 256 + t, row = id >> 4, ch = id & 15;
                int s = sb + row, kt = s >> 5, key = s & 31;
                int kb = ((c0 + ch * 8) >> 3) ^ (key & 7);   // XOR swizzle (64 blocks/row)
                *(float4*)&Ko[((size_t)(b * 32 + kt)) * 16384 + key * 512 + kb * 8] =
                    *(const float4*)&Tr[row * 136 + ch * 8];
            }
        }
    } else {
        // V: stage TRANSPOSED [channel][token] in LDS
        #pragma unroll
        for (int i = 0; i < 4; ++i)
            #pragma unroll
            for (int j = 0; j < 4; ++j)
                #pragma unroll
                for (int r = 0; r < 4; ++r) {
                    int row = wm * 64 + i * 16 + quad * 4 + r;
                    int col = wn * 64 + j * 16 + lane16;
                    Tr[col * 136 + row] = f2bf(acc[i][j][r] + bias[j]);
                }
        __syncthreads();
        int c0 = n0 - 1024, b = m0 >> 10, sb = m0 & 1023;
        #pragma unroll
        for (int it = 0; it < 8; ++it) {
            int id = it * 256 + t, c = id >> 4, ch8 = id & 15;
            int key0 = sb + ch8 * 8;                  // 8 consecutive keys
            int kt = key0 >> 5;
            int kblk = (key0 >> 3) & 3;               // block within 4-block row
            int ch = c0 + c;
            int swz = (ch >> 1) & 3;
            *(float4*)&Vo[((size_t)(b * 32 + kt)) * 16384 + (size_t)ch * 32 +
                          ((kblk ^ swz) * 8)] =
                *(const float4*)&Tr[c * 136 + ch8 * 8];
        }
    }
}

// ---------------------------------------------------------------------------
// Flash attention v3 (byte-exact revert to the 103.4 µs round-0 kernel):
// producer/consumer wave specialization.
// Block = 64 queries, 512 thr / 8 waves, full 1024 keys in 32-key tiles.
//  Waves 0-3 (producers, (qs,kh)): QK for 32q x 16 keys via 16x16x32, Q held
//    as TWO A-frag sets (128 VGPR) -> each K B-read feeds 2 MFMAs. exp() ->
//    P image (double-buffered) + per-row l partials.
//  Waves 4-7 (consumers, (qs2,chh)): PV via 32x32x16: O^T[256ch x 32q],
//    A=V^T from LDS (1 read / 16384-FLOP MFMA), B=P^T read once per key-16
//    chunk and reused across 8 ch-blocks. Consumers lag producers by 1 tile.
// One barrier per tile; K/V/P double-buffered; stages issued right after the
// barrier fly under the whole compute phase. All LDS patterns bank-uniform.
// ---------------------------------------------------------------------------
__global__ __launch_bounds__(512, 2) void flash_attn(
    const u16* __restrict__ Q, const u16* __restrict__ Kt,
    const u16* __restrict__ Vt, u16* __restrict__ O) {
    int idx = blockIdx.x;
    int xcd = idx & 7, j = idx >> 3;          // XCD-aware: 4 batches per XCD
    int bz = xcd * 4 + (j >> 4);
    int qb = j & 15;                          // 64-query block

    __shared__ alignas(16) char lds[139776];
    u16*   KsB  = (u16*)lds;                  // [2][32][512]  64 KB
    u16*   VsB  = (u16*)(lds + 65536);        // [2][512][32]  64 KB
    u16*   Pb   = (u16*)(lds + 131072);       // [2][64][32]    8 KB
    float* lsum = (float*)(lds + 139264);     // [2][64]      0.5 KB

    int t = threadIdx.x, w = t >> 6, l = t & 63;
    int lane16 = l & 15, quad = l >> 4;
    int s5 = l >> 5, l31 = l & 31;

    const u16* Kb = Kt + (size_t)bz * 32 * 16384;
    const u16* Vb = Vt + (size_t)bz * 32 * 16384;

    // prologue: stage K tile 0 (each wave copies 4 KB of the 32 KB tile)
    #pragma unroll
    for (int c = 0; c < 4; ++c) {
        int ch = w * 4 + c;
        gl2lds(&Kb[ch * 512 + l * 8], &KsB[ch * 512 + l * 8]);
    }
    __syncthreads();

    if (w < 4) {
        // ================= PRODUCER =================
        int qs = w & 1, kh = w >> 1;
        int qrow = bz * 1024 + qb * 64 + qs * 32 + lane16;
        v8s qf0[16], qf1[16];
        #pragma unroll
        for (int kk = 0; kk < 16; ++kk) {
            qf0[kk] = *(const v8s*)&Q[(size_t)qrow * 512 + kk * 32 + quad * 8];
            qf1[kk] = *(const v8s*)&Q[(size_t)(qrow + 16) * 512 + kk * 32 + quad * 8];
        }
        v4f li0 = {}, li1 = {};
        int key = kh * 16 + lane16;
        int krowoff = key * 512;
        int kswz = lane16 & 7;

        for (int kt = 0; kt <= 32; ++kt) {
            if (kt + 1 < 32) {
                u16* kd = KsB + ((kt + 1) & 1) * 16384;
                const u16* ks = Kb + (size_t)(kt + 1) * 16384;
                #pragma unroll
                for (int c = 0; c < 4; ++c) {
                    int ch = w * 4 + c;
                    gl2lds(&ks[ch * 512 + l * 8], &kd[ch * 512 + l * 8]);
                }
            }
            if (kt < 32) {
                u16* vd = VsB + (kt & 1) * 16384;
                const u16* vs = Vb + (size_t)kt * 16384;
                #pragma unroll
                for (int c = 0; c < 4; ++c) {
                    int ch = w * 4 + c;
                    gl2lds(&vs[ch * 512 + l * 8], &vd[ch * 512 + l * 8]);
                }
                const u16* KsT = KsB + (kt & 1) * 16384;
                u16* Pt = Pb + (kt & 1) * 2048;
                v4f sA = {}, sB = {};
                #pragma unroll
                for (int kk = 0; kk < 16; ++kk) {
                    v8s b = *(const v8s*)&KsT[krowoff + (((kk * 4 + quad) ^ kswz) * 8)];
                    sA = MFMA16(qf0[kk], b, sA);
                    sB = MFMA16(qf1[kk], b, sB);
                }
                #pragma unroll
                for (int r = 0; r < 4; ++r) {
                    float p0 = __expf(sA[r]), p1 = __expf(sB[r]);
                    li0[r] += p0; li1[r] += p1;
                    int q0 = qs * 32 + quad * 4 + r, q1 = q0 + 16;
                    Pt[q0 * 32 + (((key >> 3) ^ ((q0 >> 1) & 3)) * 8) + (key & 7)] = f2bf(p0);
                    Pt[q1 * 32 + (((key >> 3) ^ ((q1 >> 1) & 3)) * 8) + (key & 7)] = f2bf(p1);
                }
            }
            __syncthreads();
        }
        // reduce l over the 16 keys of this wave, publish per-kh partials
        #pragma unroll
        for (int r = 0; r < 4; ++r) {
            float a = li0[r], b = li1[r];
            a += __shfl_xor(a, 1); a += __shfl_xor(a, 2);
            a += __shfl_xor(a, 4); a += __shfl_xor(a, 8);
            b += __shfl_xor(b, 1); b += __shfl_xor(b, 2);
            b += __shfl_xor(b, 4); b += __shfl_xor(b, 8);
            if (lane16 == 0) {
                lsum[kh * 64 + qs * 32 + quad * 4 + r] = a;
                lsum[kh * 64 + qs * 32 + 16 + quad * 4 + r] = b;
            }
        }
        __syncthreads();
    } else {
        // ================= CONSUMER =================
        int cw = w - 4, qs2 = cw & 1, chh = cw >> 1;
        v16f acc[8] = {};
        int q = qs2 * 32 + l31;
        int pswz = (q >> 1) & 3;

        for (int kt = 0; kt <= 32; ++kt) {
            if (kt + 1 < 32) {
                u16* kd = KsB + ((kt + 1) & 1) * 16384;
                const u16* ks = Kb + (size_t)(kt + 1) * 16384;
                #pragma unroll
                for (int c = 0; c < 4; ++c) {
                    int ch = w * 4 + c;
                    gl2lds(&ks[ch * 512 + l * 8], &kd[ch * 512 + l * 8]);
                }
            }
            if (kt < 32) {
                u16* vd = VsB + (kt & 1) * 16384;
                const u16* vs = Vb + (size_t)kt * 16384;
                #pragma unroll
                for (int c = 0; c < 4; ++c) {
                    int ch = w * 4 + c;
                    gl2lds(&vs[ch * 512 + l * 8], &vd[ch * 512 + l * 8]);
                }
            }
            if (kt >= 1) {
                int kp = (kt - 1) & 1;
                const u16* Pt  = Pb + kp * 2048;
                const u16* VsT = VsB + kp * 16384;
                #pragma unroll
                for (int kc = 0; kc < 2; ++kc) {
                    v8s pb = *(const v8s*)&Pt[q * 32 + (((kc * 2 + s5) ^ pswz) * 8)];
                    #pragma unroll
                    for (int chb = 0; chb < 8; ++chb) {
                        int ch = chh * 256 + chb * 32 + l31;
                        v8s vf = *(const v8s*)&VsT[ch * 32 +
                                                   (((kc * 2 + s5) ^ ((ch >> 1) & 3)) * 8)];
                        acc[chb] = MFMA32(vf, pb, acc[chb]);
                    }
                }
            }
            __syncthreads();
        }
        __syncthreads();   // wait for lsum
        float inv = 1.0f / (lsum[q] + lsum[64 + q]);
        int token = bz * 1024 + qb * 64 + q;
        #pragma unroll
        for (int chb = 0; chb < 8; ++chb) {
            #pragma unroll
            for (int rg = 0; rg < 4; ++rg) {
                int ch0 = chh * 256 + chb * 32 + rg * 8 + s5 * 4;
                u16 o4[4];
                #pragma unroll
                for (int i = 0; i < 4; ++i) o4[i] = f2bf(acc[chb][rg * 4 + i] * inv);
                *(uint2*)&O[(size_t)token * 512 + ch0] = *(const uint2*)o4;
            }
        }
    }
}

// ---------------------------------------------------------------------------
// Proj GEMM + residual, BK=64 with XOR-swizzled As/Bs (same scheme as
// gemm_qkv): out[b][c][token] = x + Wp @ O_b^T + bp
// ---------------------------------------------------------------------------
__global__ __launch_bounds__(256, 2) void gemm_proj(
    const u16* __restrict__ Wp, const u16* __restrict__ O,
    const float* __restrict__ x, const float* __restrict__ bp,
    float* __restrict__ out) {
    int n0 = blockIdx.x * 128, m0 = blockIdx.y * 128, b = blockIdx.z;
    __shared__ alignas(16) u16 As[128 * 64];
    __shared__ alignas(16) u16 Bs[128 * 64];
    int t = threadIdx.x, w = t >> 6, l = t & 63;
    int lane16 = l & 15, quad = l >> 4;
    int wm = w & 1, wn = w >> 1;
    v4f acc[4][4] = {};
    for (int k0 = 0; k0 < 512; k0 += 64) {
        #pragma unroll
        for (int i = 0; i < 4; ++i) {
            int id = i * 256 + t, row = id >> 3, c16 = id & 7;
            int sc = c16 ^ (row & 7);
            gl2lds(&Wp[(size_t)(m0 + row) * 512 + k0 + sc * 8], &As[row * 64 + c16 * 8]);
            gl2lds(&O[(size_t)(b * 1024 + n0 + row) * 512 + k0 + sc * 8],
                   &Bs[row * 64 + c16 * 8]);
        }
        __syncthreads();
        #pragma unroll
        for (int hh = 0; hh < 2; ++hh) {
            v8s af[4], bf[4];
            #pragma unroll
            for (int i = 0; i < 4; ++i) {
                int row = wm * 64 + i * 16 + lane16;
                af[i] = *(const v8s*)&As[row * 64 + (((hh * 4 + quad) ^ (lane16 & 7)) * 8)];
            }
            #pragma unroll
            for (int j = 0; j < 4; ++j) {
                int row = wn * 64 + j * 16 + lane16;
                bf[j] = *(const v8s*)&Bs[row * 64 + (((hh * 4 + quad) ^ (lane16 & 7)) * 8)];
            }
            #pragma unroll
            for (int i = 0; i < 4; ++i)
                #pragma unroll
                for (int j = 0; j < 4; ++j)
                    acc[i][j] = MFMA16(af[i], bf[j], acc[i][j]);
        }
        __syncthreads();
    }
    #pragma unroll
    for (int i = 0; i < 4; ++i) {
        #pragma unroll
        for (int r = 0; r < 4; ++r) {
            int row = wm * 64 + i * 16 + quad * 4 + r;
            float bia = bp[m0 + row];
            #pragma unroll
            for (int j = 0; j < 4; ++j) {
                int col = wn * 64 + j * 16 + lane16;
                size_t idx = (size_t)(b * 512 + m0 + row) * 1024 + n0 + col;
                out[idx] = acc[i][j][r] + bia + x[idx];
            }
        }
    }
}

// ---------------------------------------------------------------------------
extern "C" void kernel_launch(void* const* d_in, const int* in_sizes, int n_in,
                              void* d_out, int out_size, void* d_ws, size_t ws_size,
                              hipStream_t stream) {
    (void)in_sizes; (void)n_in; (void)out_size; (void)ws_size;
    const float* x   = (const float*)d_in[0];
    const float* gnw = (const float*)d_in[1];
    const float* gnb = (const float*)d_in[2];
    const float* wq  = (const float*)d_in[3];
    const float* bq  = (const float*)d_in[4];
    const float* wk  = (const float*)d_in[5];
    const float* bk  = (const float*)d_in[6];
    const float* wv  = (const float*)d_in[7];
    const float* bv  = (const float*)d_in[8];
    const float* wp  = (const float*)d_in[9];
    const float* bp  = (const float*)d_in[10];
    float* out = (float*)d_out;

    char* ws = (char*)d_ws;
    u16*    Wqkv  = (u16*)(ws + 0);                       // 1.5 MB
    u16*    Wp    = (u16*)(ws + 1572864);                 // 0.5 MB
    float*  bqkv  = (float*)(ws + 2097152);               // 6 KB
    float2* stats = (float2*)(ws + 2105344);              // 8 KB
    u16*    h     = (u16*)(ws + 4194304ULL);              // 32 MB (reused as O)
    u16*    Qb    = (u16*)(ws + 4194304ULL + 33554432ULL);        // 32 MB
    u16*    Kb    = (u16*)(ws + 4194304ULL + 2ULL * 33554432ULL); // 32 MB tiled/swizzled
    u16*    Vb    = (u16*)(ws + 4194304ULL + 3ULL * 33554432ULL); // 32 MB tiled/swizzled

    prep_kernel<<<4096, 256, 0, stream>>>(wq, wk, wv, wp, bq, bk, bv, Wqkv, Wp, bqkv);
    gn_stats<<<dim3(32, 32), 256, 0, stream>>>(x, stats);
    gn_apply<<<dim3(16, 32), 256, 0, stream>>>(x, stats, gnw, gnb, h);
    gemm_qkv<<<dim3(12, 256), 256, 0, stream>>>(h, Wqkv, bqkv, Qb, Kb, Vb);
    flash_attn<<<512, 512, 0, stream>>>(Qb, Kb, Vb, h /* -> O */);
    gemm_proj<<<dim3(8, 4, 32), 256, 0, stream>>>(Wp, h /* O */, x, bp, out);
}